// Round 2
// baseline (275.794 us; speedup 1.0000x reference)
//
#include <hip/hip_runtime.h>
#include <stdint.h>

// Preprocess: bilinear 1024->256 (exact: scale=4 -> coords=4i+1.5 -> avg of
// cols/rows 4i+1,4i+2 with w=0.5), reflect-pad 30, 127-tap separable Gaussian
// (zero-padded conv on the 316x316 padded image), crop to 256x256.
// fp32 in / fp32 out (reference dtype). H intermediate fp32 in ws (62 MB).
//
// K1 (hblur): block = 4 padded rows of one channel-image. Resize 2 input rows
//   -> 256-wide row, build 384-wide extended row in LDS (zeros + reflect),
//   127-tap horizontal blur via float4 sliding-window weights (W zero-padded
//   -> branch-free). Writes H[48][316][256] fp32.
// K2 (vblur): 64x64 output tile, stage 192x64 H strip in LDS, vertical
//   127-tap blur with the same sliding-window scheme, store fp32.

#define CHTOT 48         // 16*3
#define IN_W  1024
#define OUT_W 256
#define PADW  316        // 256 + 2*30
#define KTAP  127

__device__ __forceinline__ float4 f4fma(float4 v, float w, float4 a) {
    a.x = fmaf(v.x, w, a.x); a.y = fmaf(v.y, w, a.y);
    a.z = fmaf(v.z, w, a.z); a.w = fmaf(v.w, w, a.w);
    return a;
}

// W has 136 slots: W[3+t] = gauss[t] for t in [0,127), zeros elsewhere.
__device__ __forceinline__ void compute_weights(float* W, float* E, float* Ssum, int tid) {
    if (tid < 136) W[tid] = 0.f;
    if (tid < KTAP) {
        float q = (float)(tid - 63) / 21.0f;       // x / BLUR_SIGMA
        E[tid] = exp2f(-q * q);                    // exp2, matching reference
    }
    __syncthreads();
    if (tid == 0) {
        float s = 0.f;
        for (int t = 0; t < KTAP; ++t) s += E[t];
        *Ssum = s;
    }
    __syncthreads();
    if (tid < KTAP) W[3 + tid] = E[tid] / *Ssum;
    __syncthreads();
}

__global__ __launch_bounds__(256) void hblur_kernel(const float* __restrict__ in,
                                                    float* __restrict__ H) {
    __shared__ float4 W4[34];       // 136 floats, zero padded
    __shared__ float4 R4s[4][96];   // 4 extended rows of 384 floats
    __shared__ float  E[KTAP];
    __shared__ float  Ssum;
    int tid = threadIdx.x;
    compute_weights((float*)W4, E, &Ssum, tid);

    int ch = blockIdx.y;
    int p0 = blockIdx.x * 4;                 // padded-row base; 79*4 = 316
    float* Rext = (float*)R4s;               // [4][384]

    // ---- resize: Rrow[j] = 0.25*(in[4r+1][4j+1]+in[4r+2][4j+1]+...) ----
    {
        int j = tid;                         // 0..255
        const size_t chbase = (size_t)ch * (IN_W * IN_W);
        #pragma unroll
        for (int rr = 0; rr < 4; ++rr) {
            int pr = p0 + rr - 30;
            int r = pr < 0 ? -pr : (pr > 255 ? 510 - pr : pr);   // reflect rows
            const float4* row1 = (const float4*)(in + chbase + (size_t)(4 * r + 1) * IN_W);
            const float4* row2 = row1 + (IN_W / 4);
            float4 a = row1[j];              // floats 4j..4j+3; need .y .z
            float4 b = row2[j];
            float m1 = 0.5f * a.y + 0.5f * b.y;   // axis2 (rows) first
            float m2 = 0.5f * a.z + 0.5f * b.z;
            Rext[rr * 384 + 63 + j] = 0.5f * m1 + 0.5f * m2;  // then axis3
        }
    }
    __syncthreads();
    // ---- borders: Rext[33+q] = (0<=q<316) ? Rrow[reflect(q-30)] : 0 ----
    #pragma unroll
    for (int rr = 0; rr < 4; ++rr) {
        float* Rx = Rext + rr * 384;
        if (tid < 33) {
            Rx[tid] = 0.f;                                     // q in [-33,0)
        } else if (tid < 63) {
            Rx[tid] = Rx[126 - tid];                           // mirror left
        } else if (tid >= 64 && tid < 94) {
            int q = 286 + (tid - 64);                          // q in [286,316)
            Rx[33 + q] = Rx[603 - q];                          // mirror right
        } else if (tid >= 96 && tid < 131) {
            Rx[253 + tid] = 0.f;                               // idx [349,384)
        }
    }
    __syncthreads();

    // ---- horizontal blur: acc_j = sum_t W[3+t] * Rext[4l + j + t] ----
    int g = tid >> 6;                        // wave-uniform row select
    int l = tid & 63;
    const float4* Rv = (const float4*)(Rext + g * 384);
    float acc0 = 0.f, acc1 = 0.f, acc2 = 0.f, acc3 = 0.f;
    float4 wlo = W4[0];
    #pragma unroll
    for (int i = 0; i < 33; ++i) {
        float4 whi = W4[i + 1];
        float4 v = Rv[l + i];
        acc0 = fmaf(v.x, wlo.w, acc0); acc0 = fmaf(v.y, whi.x, acc0);
        acc0 = fmaf(v.z, whi.y, acc0); acc0 = fmaf(v.w, whi.z, acc0);
        acc1 = fmaf(v.x, wlo.z, acc1); acc1 = fmaf(v.y, wlo.w, acc1);
        acc1 = fmaf(v.z, whi.x, acc1); acc1 = fmaf(v.w, whi.y, acc1);
        acc2 = fmaf(v.x, wlo.y, acc2); acc2 = fmaf(v.y, wlo.z, acc2);
        acc2 = fmaf(v.z, wlo.w, acc2); acc2 = fmaf(v.w, whi.x, acc2);
        acc3 = fmaf(v.x, wlo.x, acc3); acc3 = fmaf(v.y, wlo.y, acc3);
        acc3 = fmaf(v.z, wlo.z, acc3); acc3 = fmaf(v.w, wlo.w, acc3);
        wlo = whi;
    }
    int p = p0 + g;
    ((float4*)H)[((size_t)ch * PADW + p) * 64 + l] = make_float4(acc0, acc1, acc2, acc3);
}

__global__ __launch_bounds__(256) void vblur_kernel(const float* __restrict__ H,
                                                    float* __restrict__ out) {
    __shared__ float4 W4[34];
    __shared__ float  E[KTAP];
    __shared__ float  Ssum;
    __shared__ float4 T[192 * 16];           // 192 rows x 64 fp32 cols (48 KB)
    int tid = threadIdx.x;
    compute_weights((float*)W4, E, &Ssum, tid);

    int ch = blockIdx.y;
    int xt = blockIdx.x & 3;                 // 4 x-tiles of 64 cols
    int yt = blockIdx.x >> 2;                // 4 y-tiles of 64 rows
    int x0f4 = xt * 16;                      // float4 column base
    int y0 = yt * 64;

    const float4* H4 = (const float4*)H;
    for (int idx = tid; idx < 192 * 16; idx += 256) {
        int rr = idx >> 4, fx = idx & 15;
        int r = y0 - 33 + rr;                // H row (zero outside [0,316))
        float4 v = make_float4(0.f, 0.f, 0.f, 0.f);
        if (r >= 0 && r < PADW) v = H4[((size_t)ch * PADW + r) * 64 + x0f4 + fx];
        T[idx] = v;
    }
    __syncthreads();

    int cg = tid & 15;                       // float4 col within tile
    int g  = tid >> 4;                       // 0..15 -> output rows 4g..4g+3
    float4 acc0 = make_float4(0,0,0,0), acc1 = acc0, acc2 = acc0, acc3 = acc0;
    float4 wlo = W4[0];
    #pragma unroll
    for (int i = 0; i < 33; ++i) {
        float4 whi = W4[i + 1];
        int base = (4 * g + 4 * i) * 16 + cg;   // max row 188+3 = 191
        float4 v0 = T[base];
        float4 v1 = T[base + 16];
        float4 v2 = T[base + 32];
        float4 v3 = T[base + 48];
        acc0 = f4fma(v0, wlo.w, acc0); acc0 = f4fma(v1, whi.x, acc0);
        acc0 = f4fma(v2, whi.y, acc0); acc0 = f4fma(v3, whi.z, acc0);
        acc1 = f4fma(v0, wlo.z, acc1); acc1 = f4fma(v1, wlo.w, acc1);
        acc1 = f4fma(v2, whi.x, acc1); acc1 = f4fma(v3, whi.y, acc1);
        acc2 = f4fma(v0, wlo.y, acc2); acc2 = f4fma(v1, wlo.z, acc2);
        acc2 = f4fma(v2, wlo.w, acc2); acc2 = f4fma(v3, whi.x, acc2);
        acc3 = f4fma(v0, wlo.x, acc3); acc3 = f4fma(v1, wlo.y, acc3);
        acc3 = f4fma(v2, wlo.z, acc3); acc3 = f4fma(v3, wlo.w, acc3);
        wlo = whi;
    }

    float4* o4 = (float4*)out;
    float4 accs[4] = {acc0, acc1, acc2, acc3};
    #pragma unroll
    for (int j = 0; j < 4; ++j) {
        int y = y0 + 4 * g + j;
        o4[((size_t)ch * OUT_W + y) * 64 + xt * 16 + cg] = accs[j];
    }
}

extern "C" void kernel_launch(void* const* d_in, const int* in_sizes, int n_in,
                              void* d_out, int out_size, void* d_ws, size_t ws_size,
                              hipStream_t stream) {
    const float* in = (const float*)d_in[0];
    float* out = (float*)d_out;
    float* H = (float*)d_ws;                 // 48*316*256 fp32 = 62 MB

    hblur_kernel<<<dim3(79, CHTOT), dim3(256), 0, stream>>>(in, H);
    vblur_kernel<<<dim3(16, CHTOT), dim3(256), 0, stream>>>(H, out);
}

// Round 3
// 272.173 us; speedup vs baseline: 1.0133x; 1.0133x over previous
//
#include <hip/hip_runtime.h>
#include <stdint.h>

// Preprocess: bilinear 1024->256 (exact: scale=4 -> coords=4i+1.5 -> avg of
// cols/rows 4i+1,4i+2, w=0.5), reflect-pad 30, 127-tap separable Gaussian
// (zero-padded conv on 316x316), crop to 256x256. fp32 in / fp32 out.
//
// R3 changes vs R2:
//  - weights: serial 127-elem sum (tid==0) -> wave-shuffle parallel reduction
//  - H intermediate stored as fp16 (halves H HBM traffic; |H|<~3, fp16 rel
//    err 4.9e-4, vertical 127-tap average crushes it to ~1e-5 at the output)

#define CHTOT 48         // 16*3
#define IN_W  1024
#define OUT_W 256
#define PADW  316        // 256 + 2*30
#define KTAP  127

typedef _Float16 half_t;
typedef __attribute__((ext_vector_type(4))) _Float16 half4;

__device__ __forceinline__ float4 f4fma(float4 v, float w, float4 a) {
    a.x = fmaf(v.x, w, a.x); a.y = fmaf(v.y, w, a.y);
    a.z = fmaf(v.z, w, a.z); a.w = fmaf(v.w, w, a.w);
    return a;
}

// W has 136 slots: W[3+t] = gauss[t] for t in [0,127), zeros elsewhere.
// Parallel-reduction normalization (no serial LDS chain).
__device__ __forceinline__ void compute_weights(float* W, float* partial, int tid) {
    float e = 0.f;
    if (tid < KTAP) {
        float q = (float)(tid - 63) * (1.0f / 21.0f);   // x / BLUR_SIGMA
        e = exp2f(-q * q);                              // exp2 per reference
    }
    float s = e;
    #pragma unroll
    for (int off = 32; off >= 1; off >>= 1) s += __shfl_down(s, off, 64);
    if ((tid & 63) == 0) partial[tid >> 6] = s;
    if (tid < 136) W[tid] = 0.f;
    __syncthreads();
    float S = partial[0] + partial[1] + partial[2] + partial[3];
    if (tid < KTAP) W[3 + tid] = e / S;
    __syncthreads();
}

__global__ __launch_bounds__(256) void hblur_kernel(const float* __restrict__ in,
                                                    half_t* __restrict__ H) {
    __shared__ float4 W4[34];       // 136 floats, zero padded
    __shared__ float4 R4s[4][96];   // 4 extended rows of 384 floats
    __shared__ float  partial[4];
    int tid = threadIdx.x;
    compute_weights((float*)W4, partial, tid);

    int ch = blockIdx.y;
    int p0 = blockIdx.x * 4;                 // padded-row base; 79*4 = 316
    float* Rext = (float*)R4s;               // [4][384]

    // ---- resize: Rrow[j] = 0.25*(in[4r+1][4j+1]+in[4r+2][4j+1]+...) ----
    {
        int j = tid;                         // 0..255
        const size_t chbase = (size_t)ch * (IN_W * IN_W);
        #pragma unroll
        for (int rr = 0; rr < 4; ++rr) {
            int pr = p0 + rr - 30;
            int r = pr < 0 ? -pr : (pr > 255 ? 510 - pr : pr);   // reflect rows
            const float4* row1 = (const float4*)(in + chbase + (size_t)(4 * r + 1) * IN_W);
            const float4* row2 = row1 + (IN_W / 4);
            float4 a = row1[j];              // floats 4j..4j+3; need .y .z
            float4 b = row2[j];
            float m1 = 0.5f * a.y + 0.5f * b.y;   // axis2 (rows) first
            float m2 = 0.5f * a.z + 0.5f * b.z;
            Rext[rr * 384 + 63 + j] = 0.5f * m1 + 0.5f * m2;  // then axis3
        }
    }
    __syncthreads();
    // ---- borders: Rext[33+q] = (0<=q<316) ? Rrow[reflect(q-30)] : 0 ----
    #pragma unroll
    for (int rr = 0; rr < 4; ++rr) {
        float* Rx = Rext + rr * 384;
        if (tid < 33) {
            Rx[tid] = 0.f;                                     // q in [-33,0)
        } else if (tid < 63) {
            Rx[tid] = Rx[126 - tid];                           // mirror left
        } else if (tid >= 64 && tid < 94) {
            int q = 286 + (tid - 64);                          // q in [286,316)
            Rx[33 + q] = Rx[603 - q];                          // mirror right
        } else if (tid >= 96 && tid < 131) {
            Rx[253 + tid] = 0.f;                               // idx [349,384)
        }
    }
    __syncthreads();

    // ---- horizontal blur: acc_j = sum_t W[3+t] * Rext[4l + j + t] ----
    int g = tid >> 6;                        // wave-uniform row select
    int l = tid & 63;
    const float4* Rv = (const float4*)(Rext + g * 384);
    float acc0 = 0.f, acc1 = 0.f, acc2 = 0.f, acc3 = 0.f;
    float4 wlo = W4[0];
    #pragma unroll
    for (int i = 0; i < 33; ++i) {
        float4 whi = W4[i + 1];
        float4 v = Rv[l + i];
        acc0 = fmaf(v.x, wlo.w, acc0); acc0 = fmaf(v.y, whi.x, acc0);
        acc0 = fmaf(v.z, whi.y, acc0); acc0 = fmaf(v.w, whi.z, acc0);
        acc1 = fmaf(v.x, wlo.z, acc1); acc1 = fmaf(v.y, wlo.w, acc1);
        acc1 = fmaf(v.z, whi.x, acc1); acc1 = fmaf(v.w, whi.y, acc1);
        acc2 = fmaf(v.x, wlo.y, acc2); acc2 = fmaf(v.y, wlo.z, acc2);
        acc2 = fmaf(v.z, wlo.w, acc2); acc2 = fmaf(v.w, whi.x, acc2);
        acc3 = fmaf(v.x, wlo.x, acc3); acc3 = fmaf(v.y, wlo.y, acc3);
        acc3 = fmaf(v.z, wlo.z, acc3); acc3 = fmaf(v.w, wlo.w, acc3);
        wlo = whi;
    }
    int p = p0 + g;
    half4 hv;
    hv.x = (half_t)acc0; hv.y = (half_t)acc1; hv.z = (half_t)acc2; hv.w = (half_t)acc3;
    ((half4*)H)[((size_t)ch * PADW + p) * 64 + l] = hv;
}

__global__ __launch_bounds__(256) void vblur_kernel(const half_t* __restrict__ H,
                                                    float* __restrict__ out) {
    __shared__ float4 W4[34];
    __shared__ float  partial[4];
    __shared__ float4 T[192 * 16];           // 192 rows x 64 fp32 cols (48 KB)
    int tid = threadIdx.x;
    compute_weights((float*)W4, partial, tid);

    int ch = blockIdx.y;
    int xt = blockIdx.x & 3;                 // 4 x-tiles of 64 cols
    int yt = blockIdx.x >> 2;                // 4 y-tiles of 64 rows
    int x0h4 = xt * 16;                      // half4 column base
    int y0 = yt * 64;

    const half4* H4 = (const half4*)H;
    for (int idx = tid; idx < 192 * 16; idx += 256) {
        int rr = idx >> 4, fx = idx & 15;
        int r = y0 - 33 + rr;                // H row (zero outside [0,316))
        float4 v = make_float4(0.f, 0.f, 0.f, 0.f);
        if (r >= 0 && r < PADW) {
            half4 h = H4[((size_t)ch * PADW + r) * 64 + x0h4 + fx];
            v = make_float4((float)h.x, (float)h.y, (float)h.z, (float)h.w);
        }
        T[idx] = v;
    }
    __syncthreads();

    int cg = tid & 15;                       // float4 col within tile
    int g  = tid >> 4;                       // 0..15 -> output rows 4g..4g+3
    float4 acc0 = make_float4(0,0,0,0), acc1 = acc0, acc2 = acc0, acc3 = acc0;
    float4 wlo = W4[0];
    #pragma unroll
    for (int i = 0; i < 33; ++i) {
        float4 whi = W4[i + 1];
        int base = (4 * g + 4 * i) * 16 + cg;   // max row 188+3 = 191
        float4 v0 = T[base];
        float4 v1 = T[base + 16];
        float4 v2 = T[base + 32];
        float4 v3 = T[base + 48];
        acc0 = f4fma(v0, wlo.w, acc0); acc0 = f4fma(v1, whi.x, acc0);
        acc0 = f4fma(v2, whi.y, acc0); acc0 = f4fma(v3, whi.z, acc0);
        acc1 = f4fma(v0, wlo.z, acc1); acc1 = f4fma(v1, wlo.w, acc1);
        acc1 = f4fma(v2, whi.x, acc1); acc1 = f4fma(v3, whi.y, acc1);
        acc2 = f4fma(v0, wlo.y, acc2); acc2 = f4fma(v1, wlo.z, acc2);
        acc2 = f4fma(v2, wlo.w, acc2); acc2 = f4fma(v3, whi.x, acc2);
        acc3 = f4fma(v0, wlo.x, acc3); acc3 = f4fma(v1, wlo.y, acc3);
        acc3 = f4fma(v2, wlo.z, acc3); acc3 = f4fma(v3, wlo.w, acc3);
        wlo = whi;
    }

    float4* o4 = (float4*)out;
    float4 accs[4] = {acc0, acc1, acc2, acc3};
    #pragma unroll
    for (int j = 0; j < 4; ++j) {
        int y = y0 + 4 * g + j;
        o4[((size_t)ch * OUT_W + y) * 64 + xt * 16 + cg] = accs[j];
    }
}

extern "C" void kernel_launch(void* const* d_in, const int* in_sizes, int n_in,
                              void* d_out, int out_size, void* d_ws, size_t ws_size,
                              hipStream_t stream) {
    const float* in = (const float*)d_in[0];
    float* out = (float*)d_out;
    half_t* H = (half_t*)d_ws;               // 48*316*256 fp16 = 31 MB

    hblur_kernel<<<dim3(79, CHTOT), dim3(256), 0, stream>>>(in, H);
    vblur_kernel<<<dim3(16, CHTOT), dim3(256), 0, stream>>>(H, out);
}